// Round 12
// baseline (16.286 us; speedup 1.0000x reference)
//
#include <hip/hip_runtime.h>
#include <math.h>

// VoronoiDecoder: N=65536 x S=32. 16 lanes/point (one DPP row), 2 seeds/lane,
// 1024-thr blocks, 64 points/block, grid=1024 (2 blocks/CU, 32 waves/CU).
// Cross-lane exchange and all reductions via DPP row_ror (VALU pipe) -- the
// ONLY DS traffic is 31 table reads/thread. Table: sigmoid transition window
// [icent-376, icent+376] @ TSC=2048, replicated x16 so lane l reads copy l&15
// -> bank (entry&1)<<4|(l&15): ~2-way worst typical (free). Coverage: 1
// in-lane + 7 rotations x 4 + r=8 split (branchless operand select) = 496.

#define LOG2E 1.4426950408889634f
#define EPSF  1e-8f
#define TSC   2048.0f
#define HB    376               // half-window (quant units): 9.18 sigma-args
#define SPAN  753               // 2*HB+1 entries
#define BLOCK 1024
#define PPB   64                // points per block (16 lanes each)

#define ROR_I(X, C) __builtin_amdgcn_mov_dpp((X), (C), 0xf, 0xf, false)
#define ROR_F(X, C) __int_as_float(__builtin_amdgcn_mov_dpp(                \
                        __float_as_int(X), (C), 0xf, 0xf, false))
// full 16-lane row sum via cumulative rotations (every lane gets the total)
#define RSUM16(X)                                                           \
    {                                                                       \
        (X) += ROR_F(X, 0x128);                                             \
        (X) += ROR_F(X, 0x124);                                             \
        (X) += ROR_F(X, 0x122);                                             \
        (X) += ROR_F(X, 0x121);                                             \
    }

__global__ __launch_bounds__(BLOCK, 8) void voronoi_v12(
    const float* __restrict__ points,   // (N,2)
    const float* __restrict__ seeds,    // (32,2)
    const float* __restrict__ w_raw,    // (1,)
    const float* __restrict__ theta,    // (32,)
    const float* __restrict__ a_raw,    // (32,)
    float* __restrict__ out,            // (N,)
    int N)
{
    __shared__ float s_tab[SPAN * 16];  // 48.2 KB replicated window table
    __shared__ float s_su[32], s_sv[32], s_m00[32], s_m01[32], s_m11[32];

    const int t = threadIdx.x;

    // uniform band half-width
    const float wr = w_raw[0];
    const float sg = __builtin_amdgcn_rcpf(1.0f + exp2f(wr * (-LOG2E / 5.0f)));
    const float w  = 0.005f + 0.495f * sg;

    // transition window [T1, T1+SPAN-1] around icent
    const int icent = (int)fmaf(w, TSC, 0.5f);
    const int T1 = icent > HB ? icent - HB : 0;
    const int T2 = T1 + (SPAN - 1);

    // seed metrics, pre-scaled so sqrt lands in quant units (2x folded in m01)
    if (t < 32) {
        const float x  = a_raw[t];
        const float z  = exp2f(2.0f * LOG2E * x);
        const float th = (z - 1.0f) * __builtin_amdgcn_rcpf(z + 1.0f);  // tanh
        const float a  = 0.75f * th + 1.25f;
        const float ia = __builtin_amdgcn_rcpf(a + EPSF);
        const float cs = __cosf(theta[t]);
        const float sn = __sinf(theta[t]);
        const float S2 = TSC * TSC;
        s_m00[t] = (a * cs * cs + ia * sn * sn) * S2;
        s_m01[t] = (2.0f * cs * sn * (ia - a)) * S2;
        s_m11[t] = (a * sn * sn + ia * cs * cs) * S2;
        s_su[t]  = seeds[2 * t];
        s_sv[t]  = seeds[2 * t + 1];
    }
    // build window table, 16 replicas per entry (4 x float4 stores)
    if (t < SPAN) {
        const float arg = fmaf(-(float)(T1 + t), 50.0f / TSC, 50.0f * w);
        const float val = __builtin_amdgcn_rcpf(1.0f + exp2f(-arg * LOG2E));
        float4 v4; v4.x = val; v4.y = val; v4.z = val; v4.w = val;
        float4* dst = (float4*)&s_tab[t << 4];
        dst[0] = v4; dst[1] = v4; dst[2] = v4; dst[3] = v4;
    }
    __syncthreads();   // only barrier

    const int rl = t & 15;                      // lane within the point row
    const int p  = blockIdx.x * PPB + (t >> 4);
    if (p >= N) return;

    const int s0 = rl * 2;
    const float2 su = *(const float2*)&s_su[s0];
    const float2 sv = *(const float2*)&s_sv[s0];
    const float2 m0 = *(const float2*)&s_m00[s0];
    const float2 m1 = *(const float2*)&s_m01[s0];
    const float2 m2 = *(const float2*)&s_m11[s0];

    const float2 uv = ((const float2*)points)[p];
    const float u = uv.x, v = uv.y;

    const float EPS_Q = 1e-8f * TSC * TSC;
    float d0, d1;
#define DIST(SU, SV, M00, M01, M11, OUTD)                                   \
    {                                                                       \
        float du = u - (SU); du -= rintf(du);                               \
        float dv = v - (SV); dv -= rintf(dv);                               \
        float q = fmaf(du * du, (M00),                                      \
                  fmaf(du * dv, (M01),                                      \
                  fmaf(dv * dv, (M11), EPS_Q)));                            \
        (OUTD) = sqrtf(q);                                                  \
    }
    DIST(su.x, sv.x, m0.x, m1.x, m2.x, d0)
    DIST(su.y, sv.y, m0.y, m1.y, m2.y, d1)

    // softmax over 32 seeds (16 lanes x 2); exponents >= -29, no max-sub
    const float cE = -(20.0f * LOG2E) / TSC;
    const float e0 = exp2f(d0 * cE);
    const float e1 = exp2f(d1 * cE);
    float Z = e0 + e1;
    RSUM16(Z)
    const float rcpZ = __builtin_amdgcn_rcpf(Z);
    const float w0 = e0 * rcpZ;
    const float w1 = e1 * rcpZ;
    float sq = fmaf(w0, w0, w1 * w1);

    // quantize, pre-shifted <<6 (16 replicas x 4 bytes)
    const int q0 = ((int)(d0 + 0.5f)) << 6;
    const int q1 = ((int)(d1 + 0.5f)) << 6;

    const int loS = T1 << 6, hiS = T2 << 6;
    const int adj = (rl << 2) - loS;            // fold copy-select + T1 shift
    const char* tb = (const char*)s_tab;

#define TB(QA, QB, WJ, ACC)                                                 \
    {                                                                       \
        const int hi = (QA) > (QB) ? (QA) : (QB);                           \
        const int lo = (QA) > (QB) ? (QB) : (QA);                           \
        int df = hi - lo;                                                   \
        df = df > loS ? df : loS;                                           \
        df = df < hiS ? df : hiS;                                           \
        const float B = *(const float*)(tb + (df + adj));                   \
        (ACC) = fmaf((WJ), B, (ACC));                                       \
    }

    float acc0 = 0.0f, acc1 = 0.0f;
    TB(q0, q1, w1, acc0)                        // in-lane pair

    int rq0 = q0, rq1 = q1;
    float rw0 = w0, rw1 = w1;
#define STEP                                                                \
    {                                                                       \
        rq0 = ROR_I(rq0, 0x121); rq1 = ROR_I(rq1, 0x121);                   \
        rw0 = ROR_F(rw0, 0x121); rw1 = ROR_F(rw1, 0x121);                   \
        TB(q0, rq0, rw0, acc0)                                              \
        TB(q0, rq1, rw1, acc0)                                              \
        TB(q1, rq0, rw0, acc1)                                              \
        TB(q1, rq1, rw1, acc1)                                              \
    }
    STEP STEP STEP STEP STEP STEP STEP          // r = 1..7

    // r=8: complementary halves; branchless operand select covers each of the
    // 4 seed-combos exactly once across the lane pair {rl, rl+8}
    {
        rq0 = ROR_I(rq0, 0x121); rq1 = ROR_I(rq1, 0x121);
        rw0 = ROR_F(rw0, 0x121); rw1 = ROR_F(rw1, 0x121);
        const bool lo8 = (rl < 8);
        const int   qs = lo8 ? q0 : q1;
        const float ws = lo8 ? w0 : w1;
        float accT = 0.0f;
        TB(qs, rq0, rw0, accT)
        TB(qs, rq1, rw1, accT)
        acc0 += lo8 ? accT : 0.0f;              // fold into matching acc
        acc1 += lo8 ? 0.0f : accT;
    }

    float nb = fmaf(w0, acc0, w1 * acc1);
    RSUM16(nb)
    RSUM16(sq)

    // pair mass: sum_{i<j} w_i w_j = (1 - sum w^2)/2
    const float den   = fmaxf(0.5f * (1.0f - sq), 0.0f) + EPSF;
    const float ratio = nb * __builtin_amdgcn_rcpf(den);
    const float rho   = 1.0f - exp2f(ratio * (-8.0f * LOG2E));
    if (rl == 0) out[p] = rho;
}

extern "C" void kernel_launch(void* const* d_in, const int* in_sizes, int n_in,
                              void* d_out, int out_size, void* d_ws, size_t ws_size,
                              hipStream_t stream) {
    const float* points = (const float*)d_in[0];
    const float* seeds  = (const float*)d_in[1];
    const float* w_raw  = (const float*)d_in[2];
    const float* theta  = (const float*)d_in[3];
    const float* a_raw  = (const float*)d_in[4];
    float* out = (float*)d_out;

    const int N = in_sizes[0] / 2;              // 65536
    const int grid = (N + PPB - 1) / PPB;       // 1024 blocks

    voronoi_v12<<<grid, BLOCK, 0, stream>>>(points, seeds, w_raw, theta, a_raw,
                                            out, N);
}

// Round 13
// 15.458 us; speedup vs baseline: 1.0535x; 1.0535x over previous
//
#include <hip/hip_runtime.h>
#include <math.h>

// VoronoiDecoder: N=65536 x S=32. 8 lanes/point, 4 seeds/lane, 512-thr blocks,
// 64 points/block, grid=1024 (4 blocks/CU exact). R11 structure (best: 15.66us)
// with the table WINDOWED to [0, icent+HB] (runtime size, typically ~1780
// entries -> 4 build iterations instead of 9): cuts ~1.5us of barrier-
// serialized build prologue for +1 VALU (v_min) per pair diff. Tail clamp
// reads table[T2] ~= 1.1e-4 (exact sigma there), error negligible.

#define LOG2E 1.4426950408889634f
#define EPSF  1e-8f
#define TSC   4096.0f           // distance quant units per 1.0
#define HB    752               // transition half-width: 9.18 sigma-args
#define TAB_N 2816              // static bound: icent<=2048 -> span<=2801
#define BLOCK 512
#define PPB   64                // points per block
#define SSTR  40                // slab row stride (words): 2-way banks = free

// in-place add of quad_perm-permuted value (exact xor1/xor2 within quads)
#define DPP_ADD(X, CTRL)                                                   \
    (X) += __int_as_float(__builtin_amdgcn_mov_dpp(                        \
               __float_as_int(X), (CTRL), 0xf, 0xf, false));

__global__ __launch_bounds__(BLOCK, 8) void voronoi_v13(
    const float* __restrict__ points,   // (N,2)
    const float* __restrict__ seeds,    // (32,2)
    const float* __restrict__ w_raw,    // (1,)
    const float* __restrict__ theta,    // (32,)
    const float* __restrict__ a_raw,    // (32,)
    float* __restrict__ out,            // (N,)
    int N)
{
    __shared__ float    s_tab[TAB_N];
    __shared__ unsigned s_ii[PPB * SSTR];
    __shared__ float    s_ww[PPB * SSTR];
    __shared__ float    s_su[32], s_sv[32], s_m00[32], s_m01[32], s_m11[32];

    const int t = threadIdx.x;

    // uniform band half-width
    const float wr = w_raw[0];
    const float sg = __builtin_amdgcn_rcpf(1.0f + exp2f(wr * (-LOG2E / 5.0f)));
    const float w  = 0.005f + 0.495f * sg;

    // window: diffs clamped to T2 = icent + HB (sigma tail < 1.1e-4 beyond)
    const int icent = (int)fmaf(w, TSC, 0.5f);
    const int SPAN  = icent + HB + 1;           // table entries to build
    const int T2B   = (SPAN - 1) << 2;          // byte clamp for diffs

    // seed metrics, pre-scaled so sqrt lands in table units (2x folded in m01)
    if (t < 32) {
        const float x  = a_raw[t];
        const float z  = exp2f(2.0f * LOG2E * x);
        const float th = (z - 1.0f) * __builtin_amdgcn_rcpf(z + 1.0f);  // tanh
        const float a  = 0.75f * th + 1.25f;
        const float ia = __builtin_amdgcn_rcpf(a + EPSF);
        const float cs = __cosf(theta[t]);
        const float sn = __sinf(theta[t]);
        const float S2 = TSC * TSC;
        s_m00[t] = (a * cs * cs + ia * sn * sn) * S2;
        s_m01[t] = (2.0f * cs * sn * (ia - a)) * S2;
        s_m11[t] = (a * sn * sn + ia * cs * cs) * S2;
        s_su[t]  = seeds[2 * t];
        s_sv[t]  = seeds[2 * t + 1];
    }
    // windowed band table: T[k] = sigmoid((w - k/TSC)/0.02), k in [0, SPAN)
    {
        const float kC = (50.0f * LOG2E) / TSC;
        const float kB = -w * (50.0f * LOG2E);
        for (int k = t; k < SPAN; k += BLOCK) {
            const float y = exp2f(fmaf((float)k, kC, kB));
            s_tab[k] = __builtin_amdgcn_rcpf(1.0f + y);
        }
    }
    __syncthreads();   // only barrier; slab exchange below is same-wave

    const int pb = t >> 3;              // point slot (0..63)
    const int g  = t & 7;               // seed group
    const int s0 = g * 4;
    const int p  = blockIdx.x * PPB + pb;
    if (p >= N) return;

    const float4 su4  = *(const float4*)&s_su[s0];
    const float4 sv4  = *(const float4*)&s_sv[s0];
    const float4 m004 = *(const float4*)&s_m00[s0];
    const float4 m014 = *(const float4*)&s_m01[s0];
    const float4 m114 = *(const float4*)&s_m11[s0];

    const float2 uv = ((const float2*)points)[p];
    const float u = uv.x, v = uv.y;

    const float EPS_Q = 1e-8f * TSC * TSC;
    float4 d4;
#define DIST(SU, SV, M00, M01, M11, OUTD)                                  \
    {                                                                      \
        float du = u - (SU); du -= rintf(du);                              \
        float dv = v - (SV); dv -= rintf(dv);                              \
        float q = fmaf(du * du, (M00),                                     \
                  fmaf(du * dv, (M01),                                     \
                  fmaf(dv * dv, (M11), EPS_Q)));                           \
        (OUTD) = sqrtf(q);                                                 \
    }
    DIST(su4.x, sv4.x, m004.x, m014.x, m114.x, d4.x)
    DIST(su4.y, sv4.y, m004.y, m014.y, m114.y, d4.y)
    DIST(su4.z, sv4.z, m004.z, m014.z, m114.z, d4.z)
    DIST(su4.w, sv4.w, m004.w, m014.w, m114.w, d4.w)

    // softmax over 32 seeds (exponents bounded below ~ -29; no max-sub)
    const float cE = -(20.0f * LOG2E) / TSC;
    float4 e4;
    e4.x = exp2f(d4.x * cE);
    e4.y = exp2f(d4.y * cE);
    e4.z = exp2f(d4.z * cE);
    e4.w = exp2f(d4.w * cE);
    float Z = (e4.x + e4.y) + (e4.z + e4.w);
    DPP_ADD(Z, 0xB1)                    // + lane^1
    DPP_ADD(Z, 0x4E)                    // + lane^2
    Z += __shfl_xor(Z, 4, 64);          // + lane^4
    const float rcpZ = __builtin_amdgcn_rcpf(Z);
    float4 w4;
    w4.x = e4.x * rcpZ; w4.y = e4.y * rcpZ;
    w4.z = e4.z * rcpZ; w4.w = e4.w * rcpZ;
    float sq = w4.x * w4.x;
    sq = fmaf(w4.y, w4.y, sq);
    sq = fmaf(w4.z, w4.z, sq);
    sq = fmaf(w4.w, w4.w, sq);

    // quantize to pre-shifted byte offsets
    uint4 ii;
    ii.x = ((unsigned)(d4.x + 0.5f)) << 2;
    ii.y = ((unsigned)(d4.y + 0.5f)) << 2;
    ii.z = ((unsigned)(d4.z + 0.5f)) << 2;
    ii.w = ((unsigned)(d4.w + 0.5f)) << 2;

    // stage to this point's slab row (same-wave exchange, no barrier)
    unsigned* db = &s_ii[pb * SSTR];
    float*    wb = &s_ww[pb * SSTR];
    *(uint4*) (db + s0) = ii;
    *(float4*)(wb + s0) = w4;

    const char* tb = (const char*)s_tab;

#define TBODY(IA, IB, WJ, ACC)                                             \
    {                                                                      \
        const unsigned hi = (IA) > (IB) ? (IA) : (IB);                     \
        const unsigned lo = (IA) > (IB) ? (IB) : (IA);                     \
        unsigned df = hi - lo;                                             \
        df = df < (unsigned)T2B ? df : (unsigned)T2B;                      \
        const float B = *(const float*)(tb + df);                          \
        (ACC) = fmaf((WJ), B, (ACC));                                      \
    }

    // 6 in-lane pairs
    float b0, b1, b2, b3;
    b0 = 0.0f; b1 = 0.0f; b2 = 0.0f; b3 = 0.0f;
    TBODY(ii.x, ii.y, w4.y, b0)
    TBODY(ii.x, ii.z, w4.z, b0)
    TBODY(ii.x, ii.w, w4.w, b0)
    TBODY(ii.y, ii.z, w4.z, b1)
    TBODY(ii.y, ii.w, w4.w, b1)
    TBODY(ii.z, ii.w, w4.w, b2)

#define ROT(R)                                                             \
    {                                                                      \
        const int gj = ((g + (R)) & 7) * 4;                                \
        const uint4  ij = *(const uint4*) (db + gj);                       \
        const float4 wj = *(const float4*)(wb + gj);                       \
        TBODY(ii.x, ij.x, wj.x, b0)                                        \
        TBODY(ii.x, ij.y, wj.y, b0)                                        \
        TBODY(ii.x, ij.z, wj.z, b0)                                        \
        TBODY(ii.x, ij.w, wj.w, b0)                                        \
        TBODY(ii.y, ij.x, wj.x, b1)                                        \
        TBODY(ii.y, ij.y, wj.y, b1)                                        \
        TBODY(ii.y, ij.z, wj.z, b1)                                        \
        TBODY(ii.y, ij.w, wj.w, b1)                                        \
        TBODY(ii.z, ij.x, wj.x, b2)                                        \
        TBODY(ii.z, ij.y, wj.y, b2)                                        \
        TBODY(ii.z, ij.z, wj.z, b2)                                        \
        TBODY(ii.z, ij.w, wj.w, b2)                                        \
        TBODY(ii.w, ij.x, wj.x, b3)                                        \
        TBODY(ii.w, ij.y, wj.y, b3)                                        \
        TBODY(ii.w, ij.z, wj.z, b3)                                        \
        TBODY(ii.w, ij.w, wj.w, b3)                                        \
    }
    ROT(1)
    ROT(2)
    ROT(3)

    // ROT(4): diag/anti-diag split -- exact single coverage, 8 reads/lane
    {
        const int gj = ((g + 4) & 7) * 4;
        const uint4  ij = *(const uint4*) (db + gj);
        const float4 wj = *(const float4*)(wb + gj);
        const bool lo4 = (g < 4);
        const unsigned cA0 = lo4 ? ij.x : ij.z;
        const unsigned cA1 = lo4 ? ij.y : ij.w;
        const float    vA0 = lo4 ? wj.x : wj.z;
        const float    vA1 = lo4 ? wj.y : wj.w;
        const unsigned cB0 = lo4 ? ij.z : ij.x;
        const unsigned cB1 = lo4 ? ij.w : ij.y;
        const float    vB0 = lo4 ? wj.z : wj.x;
        const float    vB1 = lo4 ? wj.w : wj.y;
        TBODY(ii.x, cA0, vA0, b0)
        TBODY(ii.x, cA1, vA1, b0)
        TBODY(ii.y, cA0, vA0, b1)
        TBODY(ii.y, cA1, vA1, b1)
        TBODY(ii.z, cB0, vB0, b2)
        TBODY(ii.z, cB1, vB1, b2)
        TBODY(ii.w, cB0, vB0, b3)
        TBODY(ii.w, cB1, vB1, b3)
    }

    float nb = w4.x * b0;
    nb = fmaf(w4.y, b1, nb);
    nb = fmaf(w4.z, b2, nb);
    nb = fmaf(w4.w, b3, nb);

    // reduce over the point's 8 lanes (xor1/xor2 on DPP, xor4 via swizzle)
    DPP_ADD(nb, 0xB1)
    DPP_ADD(sq, 0xB1)
    DPP_ADD(nb, 0x4E)
    DPP_ADD(sq, 0x4E)
    nb += __shfl_xor(nb, 4, 64);
    sq += __shfl_xor(sq, 4, 64);

    // pair mass: sum_{i<j} w_i w_j = (1 - sum w^2)/2
    const float den   = fmaxf(0.5f * (1.0f - sq), 0.0f) + EPSF;
    const float ratio = nb * __builtin_amdgcn_rcpf(den);
    const float rho   = 1.0f - exp2f(ratio * (-8.0f * LOG2E));
    if (g == 0) out[p] = rho;
}

extern "C" void kernel_launch(void* const* d_in, const int* in_sizes, int n_in,
                              void* d_out, int out_size, void* d_ws, size_t ws_size,
                              hipStream_t stream) {
    const float* points = (const float*)d_in[0];
    const float* seeds  = (const float*)d_in[1];
    const float* w_raw  = (const float*)d_in[2];
    const float* theta  = (const float*)d_in[3];
    const float* a_raw  = (const float*)d_in[4];
    float* out = (float*)d_out;

    const int N = in_sizes[0] / 2;              // 65536
    const int grid = (N + PPB - 1) / PPB;       // 1024 blocks, 4/CU exact

    voronoi_v13<<<grid, BLOCK, 0, stream>>>(points, seeds, w_raw, theta, a_raw,
                                            out, N);
}